// Round 22
// baseline (705.235 us; speedup 1.0000x reference)
//
#include <hip/hip_runtime.h>

#define F 64
#define TPB 256
#define SCAN_B 64
#define BN_EPS 1e-5f
#define NPW 8

typedef unsigned short u16;
typedef __attribute__((ext_vector_type(8))) short v8s;
typedef __attribute__((ext_vector_type(4))) float v4f;

__device__ __forceinline__ float lane_bcast(float v, int l) {
    return __int_as_float(__builtin_amdgcn_readlane(__float_as_int(v), l));
}
__device__ __forceinline__ int lane_bcast_i(int v, int l) {
    return __builtin_amdgcn_readlane(v, l);
}
__device__ __forceinline__ float bf2f(u16 u) {
    return __uint_as_float(((unsigned int)u) << 16);
}
__device__ __forceinline__ u16 f2bf(float f) {
    unsigned int u = __float_as_uint(f);
    unsigned int r = (u + 0x7fffu + ((u >> 16) & 1u)) >> 16;   // RNE
    return (u16)r;
}

// ---- CSR build ----------------------------------------------------------

__global__ __launch_bounds__(TPB) void k_hist(const int* __restrict__ dst,
                                              int* __restrict__ deg, int E) {
    int e = blockIdx.x * blockDim.x + threadIdx.x;
    if (e < E) atomicAdd(&deg[dst[e]], 1);
}

__global__ __launch_bounds__(TPB) void k_scan_part(const int* __restrict__ deg,
                                                   int* __restrict__ part, int N) {
    __shared__ int red[TPB];
    int chunk = (N + SCAN_B - 1) / SCAN_B;
    int lo = blockIdx.x * chunk, hi = min(lo + chunk, N);
    int t = threadIdx.x;
    int s = 0;
    for (int i = lo + t; i < hi; i += TPB) s += deg[i];
    red[t] = s; __syncthreads();
    for (int d = TPB / 2; d > 0; d >>= 1) {
        if (t < d) red[t] += red[t + d];
        __syncthreads();
    }
    if (t == 0) part[blockIdx.x] = red[0];
}

__global__ __launch_bounds__(TPB) void k_scan_apply(const int* __restrict__ deg,
                                                    const int* __restrict__ part,
                                                    int* __restrict__ offs,
                                                    int* __restrict__ cursor, int N) {
    __shared__ int ts[TPB];
    __shared__ int pb_s;
    int t = threadIdx.x;
    ts[t] = (t < blockIdx.x) ? part[t] : 0;
    __syncthreads();
    for (int d = TPB / 2; d > 0; d >>= 1) {
        if (t < d) ts[t] += ts[t + d];
        __syncthreads();
    }
    if (t == 0) pb_s = ts[0];
    __syncthreads();
    int pbase = pb_s;
    __syncthreads();
    int chunk = (N + SCAN_B - 1) / SCAN_B;
    int sub = (chunk + TPB - 1) / TPB;
    int lo = blockIdx.x * chunk;
    int blockhi = min(lo + chunk, N);
    int mylo = min(lo + t * sub, blockhi);
    int myhi = min(mylo + sub, blockhi);
    int s = 0;
    for (int i = mylo; i < myhi; ++i) s += deg[i];
    ts[t] = s; __syncthreads();
    for (int d = 1; d < TPB; d <<= 1) {
        int a = (t >= d) ? ts[t - d] : 0;
        __syncthreads();
        ts[t] += a;
        __syncthreads();
    }
    int run = pbase + ts[t] - s;
    for (int i = mylo; i < myhi; ++i) {
        offs[i] = run; cursor[i] = run; run += deg[i];
    }
    if (blockIdx.x == SCAN_B - 1 && t == TPB - 1) offs[N] = pbase + ts[TPB - 1];
}

__global__ __launch_bounds__(TPB) void k_fill(const int* __restrict__ src,
                                              const int* __restrict__ dst,
                                              int* __restrict__ cursor,
                                              int* __restrict__ csr_src, int E) {
    int e = blockIdx.x * blockDim.x + threadIdx.x;
    if (e >= E) return;
    int pos = atomicAdd(&cursor[dst[e]], 1);
    csr_src[pos] = src[e];
}

// ---- MFMA prep: x16 = bf16(x); Yf = x @ Wj + bias -----------------------
__global__ __launch_bounds__(TPB, 4)
void k_prep(const float* __restrict__ x, u16* __restrict__ x16,
            const float* __restrict__ Wj, const float* __restrict__ bias,
            float* __restrict__ Yf, int N) {
    __shared__ u16 Wjl[F * F];
    int t = threadIdx.x;
    int lane = t & 63, w = t >> 6;
    int m16 = lane & 15, quad = lane >> 4;
    for (int i = t; i < F * F; i += TPB) Wjl[i] = f2bf(Wj[i]);
    __syncthreads();
    int row0 = (blockIdx.x * 4 + w) * 16;
    if (row0 >= N) return;
    v8s bfj[4][2];
#pragma unroll
    for (int nt = 0; nt < 4; ++nt)
#pragma unroll
        for (int kc = 0; kc < 2; ++kc)
#pragma unroll
            for (int j = 0; j < 8; ++j)
                bfj[nt][kc][j] = (short)Wjl[(kc * 32 + quad * 8 + j) * F + nt * 16 + m16];
    v8s a[2];
#pragma unroll
    for (int kc = 0; kc < 2; ++kc) {
        const float* xp = x + (size_t)(row0 + m16) * F + kc * 32 + quad * 8;
        float4 r0 = *(const float4*)xp;
        float4 r1 = *(const float4*)(xp + 4);
        u16 b[8] = {f2bf(r0.x), f2bf(r0.y), f2bf(r0.z), f2bf(r0.w),
                    f2bf(r1.x), f2bf(r1.y), f2bf(r1.z), f2bf(r1.w)};
#pragma unroll
        for (int j = 0; j < 8; ++j) a[kc][j] = (short)b[j];
        *(uint4*)(x16 + (size_t)(row0 + m16) * F + kc * 32 + quad * 8) = *(const uint4*)b;
    }
#pragma unroll
    for (int nt = 0; nt < 4; ++nt) {
        float bb = bias[nt * 16 + m16];
        v4f acc = {bb, bb, bb, bb};
        acc = __builtin_amdgcn_mfma_f32_16x16x32_bf16(a[0], bfj[nt][0], acc, 0, 0, 0);
        acc = __builtin_amdgcn_mfma_f32_16x16x32_bf16(a[1], bfj[nt][1], acc, 0, 0, 0);
#pragma unroll
        for (int reg = 0; reg < 4; ++reg)
            Yf[(size_t)(row0 + quad * 4 + reg) * F + nt * 16 + m16] = acc[reg];
    }
}

// ---- fused gather + GEMM1 + BN stats, cross-node pipelined --------------
// LB(256,4): 128-VGPR budget so pv[16]+pipeline state stay LIVE across the
// GEMM (R21 lesson: at LB8's 64-VGPR cap the compiler sank the prefetch
// loads to their uses, defeating the pipeline). Residency unaffected: grid
// provides only 6.1 waves/SIMD (R12 vs R15: occupancy ~40% at LB4 and LB8).
__global__ __launch_bounds__(TPB, 4)
void k_gather_gemm(const u16* __restrict__ h, const int* __restrict__ offs,
                   const int* __restrict__ csr,
                   const float* __restrict__ W, const float* __restrict__ bias,
                   u16* __restrict__ Y16, float* __restrict__ stats, int N) {
    __shared__ float Wl[F * F];
    int t = threadIdx.x;
    int lane = t & 63, w = t >> 6;
    for (int i = t; i < F * F; i += TPB) Wl[i] = W[i];
    __syncthreads();
    float bj = bias[lane];
    int node0 = (blockIdx.x * 4 + w) * NPW;
    int off_l = 0;
    if (lane <= NPW) off_l = offs[min(node0 + lane, N)];
    float s1 = 0.f, s2 = 0.f;

    // pipeline state: current node's first-16 rows in pv, next node's idx
    int startC = lane_bcast_i(off_l, 0);
    int endC   = lane_bcast_i(off_l, 1);
    int cntC   = min(endC - startC, 64);
    int idxC   = (lane < cntC) ? csr[startC + lane] : 0;
    float pv[16];
#pragma unroll
    for (int u = 0; u < 16; ++u) {
        int nu = lane_bcast_i(idxC, u);
        pv[u] = (u < cntC) ? bf2f(h[(size_t)nu * F + lane]) : 0.f;
    }
    int startN = lane_bcast_i(off_l, 1);
    int endN   = lane_bcast_i(off_l, 2);
    int cntN   = min(endN - startN, 64);
    int idxN   = (lane < cntN) ? csr[startN + lane] : 0;

#pragma unroll
    for (int r = 0; r < NPW; ++r) {
        int node = node0 + r;
        if (node >= N) break;
        // 1. agg = self + sum(prefetched first-16 rows)
        float agg = bf2f(h[(size_t)node * F + lane]);
        {
            float sA = 0.f, sB = 0.f, sC = 0.f, sD = 0.f;
#pragma unroll
            for (int u = 0; u < 4; ++u) {
                sA += pv[u]; sB += pv[4 + u]; sC += pv[8 + u]; sD += pv[12 + u];
            }
            agg += (sA + sB) + (sC + sD);
        }
        // 2. tail k=16..cntC, then batches beyond 64 (rare)
        {
            int k = 16;
            for (; k + 4 <= cntC; k += 4) {
                float v0 = bf2f(h[(size_t)lane_bcast_i(idxC, k)     * F + lane]);
                float v1 = bf2f(h[(size_t)lane_bcast_i(idxC, k + 1) * F + lane]);
                float v2 = bf2f(h[(size_t)lane_bcast_i(idxC, k + 2) * F + lane]);
                float v3 = bf2f(h[(size_t)lane_bcast_i(idxC, k + 3) * F + lane]);
                agg += (v0 + v1) + (v2 + v3);
            }
            for (; k < cntC; ++k)
                agg += bf2f(h[(size_t)lane_bcast_i(idxC, k) * F + lane]);
        }
        for (int base = startC + 64; base < endC; base += 64) {
            int c2 = endC - base; if (c2 > 64) c2 = 64;
            int idx2 = (lane < c2) ? csr[base + lane] : 0;
            int k = 0;
            for (; k + 4 <= c2; k += 4) {
                float v0 = bf2f(h[(size_t)lane_bcast_i(idx2, k)     * F + lane]);
                float v1 = bf2f(h[(size_t)lane_bcast_i(idx2, k + 1) * F + lane]);
                float v2 = bf2f(h[(size_t)lane_bcast_i(idx2, k + 2) * F + lane]);
                float v3 = bf2f(h[(size_t)lane_bcast_i(idx2, k + 3) * F + lane]);
                agg += (v0 + v1) + (v2 + v3);
            }
            for (; k < c2; ++k)
                agg += bf2f(h[(size_t)lane_bcast_i(idx2, k) * F + lane]);
        }
        // 3. rotate pipeline: issue next node's row loads before our GEMM
        if (r + 1 < NPW) {
            int sC2 = startN, eC2 = endN, cC2 = cntN, iC2 = idxN;
            if (r + 2 < NPW) {
                startN = lane_bcast_i(off_l, r + 2);
                endN   = lane_bcast_i(off_l, r + 3);
                cntN   = min(endN - startN, 64);
                idxN   = (lane < cntN) ? csr[startN + lane] : 0;
            }
#pragma unroll
            for (int u = 0; u < 16; ++u) {
                int nu = lane_bcast_i(iC2, u);
                pv[u] = (u < cC2) ? bf2f(h[(size_t)nu * F + lane]) : 0.f;
            }
            startC = sC2; endC = eC2; cntC = cC2; idxC = iC2;
        }
        // 4. GEMM from LDS W (loads for node r+1 in flight)
        float acc = bj;
#pragma unroll
        for (int f = 0; f < F; ++f) acc += lane_bcast(agg, f) * Wl[f * F + lane];
        Y16[(size_t)node * F + lane] = f2bf(acc);
        s1 += acc;
        s2 += acc * acc;
    }
    __shared__ float red[TPB];
    red[t] = s1; __syncthreads();
    if (w == 0) atomicAdd(&stats[lane], red[lane] + red[64 + lane] + red[128 + lane] + red[192 + lane]);
    __syncthreads();
    red[t] = s2; __syncthreads();
    if (w == 0) atomicAdd(&stats[64 + lane], red[lane] + red[64 + lane] + red[128 + lane] + red[192 + lane]);
}

// ---- MFMA layerB (R19-verified) -----------------------------------------
__global__ __launch_bounds__(TPB, 3)
void k_layerB(const u16* __restrict__ Y16, const float* __restrict__ stats,
              const float* __restrict__ g, const float* __restrict__ bt,
              const float* __restrict__ W2, const float* __restrict__ b2,
              const float* __restrict__ Wj,
              u16* __restrict__ Hout, float* __restrict__ Yf,
              float* __restrict__ stats5, int N, int doHead) {
    __shared__ u16 W2l[F * F];
    __shared__ u16 Wjl[F * F];
    __shared__ float scs[F], shs[F];
    __shared__ u16 hbuf[4][16 * F];
    __shared__ float cred1[F], cred2[F];
    int t = threadIdx.x;
    int lane = t & 63, w = t >> 6;
    int m16 = lane & 15, quad = lane >> 4;
    for (int i = t; i < F * F; i += TPB) {
        W2l[i] = f2bf(W2[i]);
        Wjl[i] = f2bf(Wj[i]);
    }
    if (t < F) {
        float mu = stats[t] / (float)N;
        float var = stats[F + t] / (float)N - mu * mu;
        float rs = rsqrtf(var + BN_EPS);
        float sc = rs * g[t];
        scs[t] = sc;
        shs[t] = bt[t] - mu * sc;
    }
    __syncthreads();

    int row0 = (blockIdx.x * 4 + w) * 16;
    float s1v[4] = {0.f, 0.f, 0.f, 0.f}, s2v[4] = {0.f, 0.f, 0.f, 0.f};
    if (row0 < N) {
        v8s bf2_[4][2], bfj_[4][2];
#pragma unroll
        for (int nt = 0; nt < 4; ++nt)
#pragma unroll
            for (int kc = 0; kc < 2; ++kc)
#pragma unroll
                for (int j = 0; j < 8; ++j) {
                    int k = kc * 32 + quad * 8 + j;
                    bf2_[nt][kc][j] = (short)W2l[k * F + nt * 16 + m16];
                    bfj_[nt][kc][j] = (short)Wjl[k * F + nt * 16 + m16];
                }
        v8s a1[2];
#pragma unroll
        for (int kc = 0; kc < 2; ++kc) {
            uint4 raw = *(const uint4*)(Y16 + (size_t)(row0 + m16) * F + kc * 32 + quad * 8);
            unsigned uu[4] = {raw.x, raw.y, raw.z, raw.w};
#pragma unroll
            for (int p = 0; p < 4; ++p) {
                int k0 = kc * 32 + quad * 8 + 2 * p;
                float lo = __uint_as_float(uu[p] << 16);
                float hi = __uint_as_float(uu[p] & 0xffff0000u);
                float v0 = fmaxf(lo * scs[k0] + shs[k0], 0.f);
                float v1 = fmaxf(hi * scs[k0 + 1] + shs[k0 + 1], 0.f);
                a1[kc][2 * p]     = (short)f2bf(v0);
                a1[kc][2 * p + 1] = (short)f2bf(v1);
            }
        }
        u16* hb = hbuf[w];
#pragma unroll
        for (int nt = 0; nt < 4; ++nt) {
            float bb = b2[nt * 16 + m16];
            v4f acc = {bb, bb, bb, bb};
            acc = __builtin_amdgcn_mfma_f32_16x16x32_bf16(a1[0], bf2_[nt][0], acc, 0, 0, 0);
            acc = __builtin_amdgcn_mfma_f32_16x16x32_bf16(a1[1], bf2_[nt][1], acc, 0, 0, 0);
#pragma unroll
            for (int reg = 0; reg < 4; ++reg)
                hb[(quad * 4 + reg) * F + nt * 16 + m16] = f2bf(fmaxf(acc[reg], 0.f));
        }
#pragma unroll
        for (int rr = 0; rr < 4; ++rr) {
            int row = rr * 4 + quad;
            uint2 d = *(const uint2*)(hb + row * F + m16 * 4);
            *(uint2*)(Hout + (size_t)(row0 + row) * F + m16 * 4) = d;
        }
        v8s a2[2];
#pragma unroll
        for (int kc = 0; kc < 2; ++kc)
            a2[kc] = *(const v8s*)(hb + m16 * F + kc * 32 + quad * 8);
#pragma unroll
        for (int nt = 0; nt < 4; ++nt) {
            v4f acc;
#pragma unroll
            for (int reg = 0; reg < 4; ++reg)
                acc[reg] = Yf[(size_t)(row0 + quad * 4 + reg) * F + nt * 16 + m16];
            acc = __builtin_amdgcn_mfma_f32_16x16x32_bf16(a2[0], bfj_[nt][0], acc, 0, 0, 0);
            acc = __builtin_amdgcn_mfma_f32_16x16x32_bf16(a2[1], bfj_[nt][1], acc, 0, 0, 0);
            float ss1 = 0.f, ss2 = 0.f;
#pragma unroll
            for (int reg = 0; reg < 4; ++reg) {
                float yv = acc[reg];
                Yf[(size_t)(row0 + quad * 4 + reg) * F + nt * 16 + m16] = yv;
                ss1 += yv;
                ss2 += yv * yv;
            }
            s1v[nt] = ss1;
            s2v[nt] = ss2;
        }
    }
    if (doHead) {
        if (t < F) { cred1[t] = 0.f; cred2[t] = 0.f; }
        __syncthreads();
        if (row0 < N) {
#pragma unroll
            for (int nt = 0; nt < 4; ++nt) {
                atomicAdd(&cred1[nt * 16 + m16], s1v[nt]);
                atomicAdd(&cred2[nt * 16 + m16], s2v[nt]);
            }
        }
        __syncthreads();
        if (t < F) {
            atomicAdd(&stats5[t], cred1[t]);
            atomicAdd(&stats5[F + t], cred2[t]);
        }
    }
}

// ---- MFMA head: BN(Yf)+ReLU -> @mlpW2+b2 -> pooled add into out[graph] --
__global__ __launch_bounds__(TPB, 4)
void k_final(const float* __restrict__ Yf, const float* __restrict__ stats,
             const float* __restrict__ g, const float* __restrict__ bt,
             const float* __restrict__ W2, const float* __restrict__ b2,
             const int* __restrict__ batch, float* __restrict__ out, int N) {
    __shared__ u16 W2l[F * F];
    __shared__ float scs[F], shs[F];
    int t = threadIdx.x;
    int lane = t & 63, w = t >> 6;
    int m16 = lane & 15, quad = lane >> 4;
    for (int i = t; i < F * F; i += TPB) W2l[i] = f2bf(W2[i]);
    if (t < F) {
        float mu = stats[t] / (float)N;
        float var = stats[F + t] / (float)N - mu * mu;
        float rs = rsqrtf(var + BN_EPS);
        float sc = rs * g[t];
        scs[t] = sc;
        shs[t] = bt[t] - mu * sc;
    }
    __syncthreads();
    int row0 = (blockIdx.x * 4 + w) * 16;
    if (row0 >= N) return;
    v8s bw[4][2];
#pragma unroll
    for (int nt = 0; nt < 4; ++nt)
#pragma unroll
        for (int kc = 0; kc < 2; ++kc)
#pragma unroll
            for (int j = 0; j < 8; ++j)
                bw[nt][kc][j] = (short)W2l[(kc * 32 + quad * 8 + j) * F + nt * 16 + m16];
    v8s a[2];
#pragma unroll
    for (int kc = 0; kc < 2; ++kc) {
        const float* yp = Yf + (size_t)(row0 + m16) * F + kc * 32 + quad * 8;
        float4 r0 = *(const float4*)yp;
        float4 r1 = *(const float4*)(yp + 4);
        float vals[8] = {r0.x, r0.y, r0.z, r0.w, r1.x, r1.y, r1.z, r1.w};
#pragma unroll
        for (int j = 0; j < 8; ++j) {
            int k = kc * 32 + quad * 8 + j;
            a[kc][j] = (short)f2bf(fmaxf(vals[j] * scs[k] + shs[k], 0.f));
        }
    }
    v4f accv[4];
#pragma unroll
    for (int nt = 0; nt < 4; ++nt) {
        float bb = b2[nt * 16 + m16];
        v4f acc = {bb, bb, bb, bb};
        acc = __builtin_amdgcn_mfma_f32_16x16x32_bf16(a[0], bw[nt][0], acc, 0, 0, 0);
        acc = __builtin_amdgcn_mfma_f32_16x16x32_bf16(a[1], bw[nt][1], acc, 0, 0, 0);
        accv[nt] = acc;
    }
    int gid_prev = -1;
    float psum[4] = {0.f, 0.f, 0.f, 0.f};
#pragma unroll
    for (int reg = 0; reg < 4; ++reg) {
        int gid = batch[row0 + quad * 4 + reg];
        if (gid != gid_prev) {
            if (gid_prev >= 0)
#pragma unroll
                for (int nt = 0; nt < 4; ++nt)
                    atomicAdd(&out[(size_t)gid_prev * F + nt * 16 + m16], psum[nt]);
            gid_prev = gid;
            psum[0] = psum[1] = psum[2] = psum[3] = 0.f;
        }
#pragma unroll
        for (int nt = 0; nt < 4; ++nt) psum[nt] += accv[nt][reg];
    }
    if (gid_prev >= 0)
#pragma unroll
        for (int nt = 0; nt < 4; ++nt)
            atomicAdd(&out[(size_t)gid_prev * F + nt * 16 + m16], psum[nt]);
}

// ---- launcher -----------------------------------------------------------

extern "C" void kernel_launch(void* const* d_in, const int* in_sizes, int n_in,
                              void* d_out, int out_size, void* d_ws, size_t ws_size,
                              hipStream_t stream) {
    const float* x      = (const float*)d_in[0];
    const int*   ei     = (const int*)d_in[1];
    const int*   batch  = (const int*)d_in[2];
    const float* convW1 = (const float*)d_in[3];
    const float* convb1 = (const float*)d_in[4];
    const float* convg  = (const float*)d_in[5];
    const float* convbt = (const float*)d_in[6];
    const float* convW2 = (const float*)d_in[7];
    const float* convb2 = (const float*)d_in[8];
    const float* mlpW1  = (const float*)d_in[9];
    const float* mlpb1  = (const float*)d_in[10];
    const float* mlpg   = (const float*)d_in[11];
    const float* mlpbt  = (const float*)d_in[12];
    const float* mlpW2  = (const float*)d_in[13];
    const float* mlpb2  = (const float*)d_in[14];

    const int N = in_sizes[0] / F;             // 50000
    const int E = in_sizes[1] / 2;             // 800000
    const int L = in_sizes[3] / (F * F);       // 5

    const int* src = ei;
    const int* dst = ei + E;

    char* w = (char*)d_ws;
    size_t off = 0;
    auto alloc = [&](size_t bytes) {
        void* p = w + off;
        off = (off + bytes + 255) & ~(size_t)255;
        return p;
    };
    u16*   x16     = (u16*)alloc((size_t)N * F * 2);
    u16*   hA16    = (u16*)alloc((size_t)N * F * 2);
    u16*   hB16    = (u16*)alloc((size_t)N * F * 2);
    u16*   Ytmp16  = (u16*)alloc((size_t)N * F * 2);
    float* Yf      = (float*)alloc((size_t)N * F * 4);
    int*   deg     = (int*)alloc((size_t)N * 4);
    int*   offs    = (int*)alloc((size_t)(N + 1) * 4);
    int*   cursor  = (int*)alloc((size_t)N * 4);
    int*   csr_src = (int*)alloc((size_t)E * 4);
    int*   part    = (int*)alloc((size_t)SCAN_B * 4);
    float* stats   = (float*)alloc((size_t)(L + 1) * 128 * 4);

    hipMemsetAsync(deg, 0, (size_t)N * 4, stream);
    hipMemsetAsync(stats, 0, (size_t)(L + 1) * 128 * 4, stream);
    hipMemsetAsync(d_out, 0, (size_t)out_size * 4, stream);

    const int edgeBlocks = (E + TPB - 1) / TPB;

    k_hist<<<edgeBlocks, TPB, 0, stream>>>(dst, deg, E);
    k_scan_part<<<SCAN_B, TPB, 0, stream>>>(deg, part, N);
    k_scan_apply<<<SCAN_B, TPB, 0, stream>>>(deg, part, offs, cursor, N);
    k_fill<<<edgeBlocks, TPB, 0, stream>>>(src, dst, cursor, csr_src, E);

    const int blocksA = (N + 4 * NPW - 1) / (4 * NPW);   // 1563
    const int blocksB = (N + 63) / 64;                   // MFMA tiles

    k_prep<<<blocksB, TPB, 0, stream>>>(x, x16, mlpW1, mlpb1, Yf, N);

    const u16* h_cur = x16;
    for (int l = 0; l < L; ++l) {
        u16* h_next = (l & 1) ? hB16 : hA16;
        k_gather_gemm<<<blocksA, TPB, 0, stream>>>(h_cur, offs, csr_src,
                                                   convW1 + l * F * F, convb1 + l * F,
                                                   Ytmp16, stats + l * 128, N);
        k_layerB<<<blocksB, TPB, 0, stream>>>(Ytmp16, stats + l * 128,
                                              convg + l * F, convbt + l * F,
                                              convW2 + l * F * F, convb2 + l * F,
                                              mlpW1 + (l + 1) * F * F,
                                              h_next, Yf, stats + L * 128,
                                              N, l == L - 1);
        h_cur = h_next;
    }

    k_final<<<blocksB, TPB, 0, stream>>>(Yf, stats + L * 128, mlpg, mlpbt,
                                         mlpW2, mlpb2, batch, (float*)d_out, N);
}

// Round 23
// 608.656 us; speedup vs baseline: 1.1587x; 1.1587x over previous
//
#include <hip/hip_runtime.h>

#define F 64
#define TPB 256
#define SCAN_B 64
#define BN_EPS 1e-5f
#define NPW 8

typedef unsigned short u16;
typedef __attribute__((ext_vector_type(8))) short v8s;
typedef __attribute__((ext_vector_type(4))) float v4f;

__device__ __forceinline__ float lane_bcast(float v, int l) {
    return __int_as_float(__builtin_amdgcn_readlane(__float_as_int(v), l));
}
__device__ __forceinline__ int lane_bcast_i(int v, int l) {
    return __builtin_amdgcn_readlane(v, l);
}
__device__ __forceinline__ float bf2f(u16 u) {
    return __uint_as_float(((unsigned int)u) << 16);
}
__device__ __forceinline__ u16 f2bf(float f) {
    unsigned int u = __float_as_uint(f);
    unsigned int r = (u + 0x7fffu + ((u >> 16) & 1u)) >> 16;   // RNE
    return (u16)r;
}

// ---- CSR build ----------------------------------------------------------

__global__ __launch_bounds__(TPB) void k_hist(const int* __restrict__ dst,
                                              int* __restrict__ deg, int E) {
    int e = blockIdx.x * blockDim.x + threadIdx.x;
    if (e < E) atomicAdd(&deg[dst[e]], 1);
}

__global__ __launch_bounds__(TPB) void k_scan_part(const int* __restrict__ deg,
                                                   int* __restrict__ part, int N) {
    __shared__ int red[TPB];
    int chunk = (N + SCAN_B - 1) / SCAN_B;
    int lo = blockIdx.x * chunk, hi = min(lo + chunk, N);
    int t = threadIdx.x;
    int s = 0;
    for (int i = lo + t; i < hi; i += TPB) s += deg[i];
    red[t] = s; __syncthreads();
    for (int d = TPB / 2; d > 0; d >>= 1) {
        if (t < d) red[t] += red[t + d];
        __syncthreads();
    }
    if (t == 0) part[blockIdx.x] = red[0];
}

__global__ __launch_bounds__(TPB) void k_scan_apply(const int* __restrict__ deg,
                                                    const int* __restrict__ part,
                                                    int* __restrict__ offs,
                                                    int* __restrict__ cursor, int N) {
    __shared__ int ts[TPB];
    __shared__ int pb_s;
    int t = threadIdx.x;
    ts[t] = (t < blockIdx.x) ? part[t] : 0;
    __syncthreads();
    for (int d = TPB / 2; d > 0; d >>= 1) {
        if (t < d) ts[t] += ts[t + d];
        __syncthreads();
    }
    if (t == 0) pb_s = ts[0];
    __syncthreads();
    int pbase = pb_s;
    __syncthreads();
    int chunk = (N + SCAN_B - 1) / SCAN_B;
    int sub = (chunk + TPB - 1) / TPB;
    int lo = blockIdx.x * chunk;
    int blockhi = min(lo + chunk, N);
    int mylo = min(lo + t * sub, blockhi);
    int myhi = min(mylo + sub, blockhi);
    int s = 0;
    for (int i = mylo; i < myhi; ++i) s += deg[i];
    ts[t] = s; __syncthreads();
    for (int d = 1; d < TPB; d <<= 1) {
        int a = (t >= d) ? ts[t - d] : 0;
        __syncthreads();
        ts[t] += a;
        __syncthreads();
    }
    int run = pbase + ts[t] - s;
    for (int i = mylo; i < myhi; ++i) {
        offs[i] = run; cursor[i] = run; run += deg[i];
    }
    if (blockIdx.x == SCAN_B - 1 && t == TPB - 1) offs[N] = pbase + ts[TPB - 1];
}

__global__ __launch_bounds__(TPB) void k_fill(const int* __restrict__ src,
                                              const int* __restrict__ dst,
                                              int* __restrict__ cursor,
                                              int* __restrict__ csr_src, int E) {
    int e = blockIdx.x * blockDim.x + threadIdx.x;
    if (e >= E) return;
    int pos = atomicAdd(&cursor[dst[e]], 1);
    csr_src[pos] = src[e];
}

// ---- MFMA prep: x16 = bf16(x); Yf = x @ Wj + bias -----------------------
__global__ __launch_bounds__(TPB, 4)
void k_prep(const float* __restrict__ x, u16* __restrict__ x16,
            const float* __restrict__ Wj, const float* __restrict__ bias,
            float* __restrict__ Yf, int N) {
    __shared__ u16 Wjl[F * F];
    int t = threadIdx.x;
    int lane = t & 63, w = t >> 6;
    int m16 = lane & 15, quad = lane >> 4;
    for (int i = t; i < F * F; i += TPB) Wjl[i] = f2bf(Wj[i]);
    __syncthreads();
    int row0 = (blockIdx.x * 4 + w) * 16;
    if (row0 >= N) return;
    v8s bfj[4][2];
#pragma unroll
    for (int nt = 0; nt < 4; ++nt)
#pragma unroll
        for (int kc = 0; kc < 2; ++kc)
#pragma unroll
            for (int j = 0; j < 8; ++j)
                bfj[nt][kc][j] = (short)Wjl[(kc * 32 + quad * 8 + j) * F + nt * 16 + m16];
    v8s a[2];
#pragma unroll
    for (int kc = 0; kc < 2; ++kc) {
        const float* xp = x + (size_t)(row0 + m16) * F + kc * 32 + quad * 8;
        float4 r0 = *(const float4*)xp;
        float4 r1 = *(const float4*)(xp + 4);
        u16 b[8] = {f2bf(r0.x), f2bf(r0.y), f2bf(r0.z), f2bf(r0.w),
                    f2bf(r1.x), f2bf(r1.y), f2bf(r1.z), f2bf(r1.w)};
#pragma unroll
        for (int j = 0; j < 8; ++j) a[kc][j] = (short)b[j];
        *(uint4*)(x16 + (size_t)(row0 + m16) * F + kc * 32 + quad * 8) = *(const uint4*)b;
    }
#pragma unroll
    for (int nt = 0; nt < 4; ++nt) {
        float bb = bias[nt * 16 + m16];
        v4f acc = {bb, bb, bb, bb};
        acc = __builtin_amdgcn_mfma_f32_16x16x32_bf16(a[0], bfj[nt][0], acc, 0, 0, 0);
        acc = __builtin_amdgcn_mfma_f32_16x16x32_bf16(a[1], bfj[nt][1], acc, 0, 0, 0);
#pragma unroll
        for (int reg = 0; reg < 4; ++reg)
            Yf[(size_t)(row0 + quad * 4 + reg) * F + nt * 16 + m16] = acc[reg];
    }
}

// ---- fused gather + GEMM1 + BN stats (R20 structure: LDS W, 16-deep) ----
__global__ __launch_bounds__(TPB, 8)
void k_gather_gemm(const u16* __restrict__ h, const int* __restrict__ offs,
                   const int* __restrict__ csr,
                   const float* __restrict__ W, const float* __restrict__ bias,
                   u16* __restrict__ Y16, float* __restrict__ stats, int N) {
    __shared__ float Wl[F * F];
    int t = threadIdx.x;
    int lane = t & 63, w = t >> 6;
    for (int i = t; i < F * F; i += TPB) Wl[i] = W[i];
    __syncthreads();
    float bj = bias[lane];
    int node0 = (blockIdx.x * 4 + w) * NPW;
    int off_l = 0;
    if (lane <= NPW) off_l = offs[min(node0 + lane, N)];
    float s1 = 0.f, s2 = 0.f;
    int start_n = lane_bcast_i(off_l, 0);
    int end_n   = lane_bcast_i(off_l, 1);
    int cnt_n   = min(end_n - start_n, 64);
    int idx_n   = (lane < cnt_n) ? csr[start_n + lane] : 0;
    for (int r = 0; r < NPW; ++r) {
        int node = node0 + r;
        if (node >= N) break;
        int start = start_n, end = end_n, cnt = cnt_n, idx = idx_n;
        if (r + 1 < NPW) {
            start_n = lane_bcast_i(off_l, r + 1);
            end_n   = lane_bcast_i(off_l, r + 2);
            cnt_n   = min(end_n - start_n, 64);
            idx_n   = (lane < cnt_n) ? csr[start_n + lane] : 0;
        }
        float agg = bf2f(h[(size_t)node * F + lane]);    // GIN self term (eps=0)
        {
            int k = 0;
            for (; k + 16 <= cnt; k += 16) {
                float vv[16];
#pragma unroll
                for (int u = 0; u < 16; ++u)
                    vv[u] = bf2f(h[(size_t)lane_bcast_i(idx, k + u) * F + lane]);
                float sA = 0.f, sB = 0.f, sC = 0.f, sD = 0.f;
#pragma unroll
                for (int u = 0; u < 4; ++u) {
                    sA += vv[u]; sB += vv[4 + u]; sC += vv[8 + u]; sD += vv[12 + u];
                }
                agg += (sA + sB) + (sC + sD);
            }
            for (; k + 4 <= cnt; k += 4) {
                float v0 = bf2f(h[(size_t)lane_bcast_i(idx, k)     * F + lane]);
                float v1 = bf2f(h[(size_t)lane_bcast_i(idx, k + 1) * F + lane]);
                float v2 = bf2f(h[(size_t)lane_bcast_i(idx, k + 2) * F + lane]);
                float v3 = bf2f(h[(size_t)lane_bcast_i(idx, k + 3) * F + lane]);
                agg += (v0 + v1) + (v2 + v3);
            }
            for (; k < cnt; ++k)
                agg += bf2f(h[(size_t)lane_bcast_i(idx, k) * F + lane]);
        }
        for (int base = start + 64; base < end; base += 64) {
            int c2 = end - base; if (c2 > 64) c2 = 64;
            int idx2 = (lane < c2) ? csr[base + lane] : 0;
            int k = 0;
            for (; k + 4 <= c2; k += 4) {
                float v0 = bf2f(h[(size_t)lane_bcast_i(idx2, k)     * F + lane]);
                float v1 = bf2f(h[(size_t)lane_bcast_i(idx2, k + 1) * F + lane]);
                float v2 = bf2f(h[(size_t)lane_bcast_i(idx2, k + 2) * F + lane]);
                float v3 = bf2f(h[(size_t)lane_bcast_i(idx2, k + 3) * F + lane]);
                agg += (v0 + v1) + (v2 + v3);
            }
            for (; k < c2; ++k)
                agg += bf2f(h[(size_t)lane_bcast_i(idx2, k) * F + lane]);
        }
        float acc = bj;
#pragma unroll
        for (int f = 0; f < F; ++f) acc += lane_bcast(agg, f) * Wl[f * F + lane];
        Y16[(size_t)node * F + lane] = f2bf(acc);
        s1 += acc;
        s2 += acc * acc;
    }
    __shared__ float red[TPB];
    red[t] = s1; __syncthreads();
    if (w == 0) atomicAdd(&stats[lane], red[lane] + red[64 + lane] + red[128 + lane] + red[192 + lane]);
    __syncthreads();
    red[t] = s2; __syncthreads();
    if (w == 0) atomicAdd(&stats[64 + lane], red[lane] + red[64 + lane] + red[128 + lane] + red[192 + lane]);
}

// ---- MFMA layerB (R19-verified) -----------------------------------------
__global__ __launch_bounds__(TPB, 3)
void k_layerB(const u16* __restrict__ Y16, const float* __restrict__ stats,
              const float* __restrict__ g, const float* __restrict__ bt,
              const float* __restrict__ W2, const float* __restrict__ b2,
              const float* __restrict__ Wj,
              u16* __restrict__ Hout, float* __restrict__ Yf,
              float* __restrict__ stats5, int N, int doHead) {
    __shared__ u16 W2l[F * F];
    __shared__ u16 Wjl[F * F];
    __shared__ float scs[F], shs[F];
    __shared__ u16 hbuf[4][16 * F];
    __shared__ float cred1[F], cred2[F];
    int t = threadIdx.x;
    int lane = t & 63, w = t >> 6;
    int m16 = lane & 15, quad = lane >> 4;
    for (int i = t; i < F * F; i += TPB) {
        W2l[i] = f2bf(W2[i]);
        Wjl[i] = f2bf(Wj[i]);
    }
    if (t < F) {
        float mu = stats[t] / (float)N;
        float var = stats[F + t] / (float)N - mu * mu;
        float rs = rsqrtf(var + BN_EPS);
        float sc = rs * g[t];
        scs[t] = sc;
        shs[t] = bt[t] - mu * sc;
    }
    __syncthreads();

    int row0 = (blockIdx.x * 4 + w) * 16;
    float s1v[4] = {0.f, 0.f, 0.f, 0.f}, s2v[4] = {0.f, 0.f, 0.f, 0.f};
    if (row0 < N) {
        v8s bf2_[4][2], bfj_[4][2];
#pragma unroll
        for (int nt = 0; nt < 4; ++nt)
#pragma unroll
            for (int kc = 0; kc < 2; ++kc)
#pragma unroll
                for (int j = 0; j < 8; ++j) {
                    int k = kc * 32 + quad * 8 + j;
                    bf2_[nt][kc][j] = (short)W2l[k * F + nt * 16 + m16];
                    bfj_[nt][kc][j] = (short)Wjl[k * F + nt * 16 + m16];
                }
        v8s a1[2];
#pragma unroll
        for (int kc = 0; kc < 2; ++kc) {
            uint4 raw = *(const uint4*)(Y16 + (size_t)(row0 + m16) * F + kc * 32 + quad * 8);
            unsigned uu[4] = {raw.x, raw.y, raw.z, raw.w};
#pragma unroll
            for (int p = 0; p < 4; ++p) {
                int k0 = kc * 32 + quad * 8 + 2 * p;
                float lo = __uint_as_float(uu[p] << 16);
                float hi = __uint_as_float(uu[p] & 0xffff0000u);
                float v0 = fmaxf(lo * scs[k0] + shs[k0], 0.f);
                float v1 = fmaxf(hi * scs[k0 + 1] + shs[k0 + 1], 0.f);
                a1[kc][2 * p]     = (short)f2bf(v0);
                a1[kc][2 * p + 1] = (short)f2bf(v1);
            }
        }
        u16* hb = hbuf[w];
#pragma unroll
        for (int nt = 0; nt < 4; ++nt) {
            float bb = b2[nt * 16 + m16];
            v4f acc = {bb, bb, bb, bb};
            acc = __builtin_amdgcn_mfma_f32_16x16x32_bf16(a1[0], bf2_[nt][0], acc, 0, 0, 0);
            acc = __builtin_amdgcn_mfma_f32_16x16x32_bf16(a1[1], bf2_[nt][1], acc, 0, 0, 0);
#pragma unroll
            for (int reg = 0; reg < 4; ++reg)
                hb[(quad * 4 + reg) * F + nt * 16 + m16] = f2bf(fmaxf(acc[reg], 0.f));
        }
#pragma unroll
        for (int rr = 0; rr < 4; ++rr) {
            int row = rr * 4 + quad;
            uint2 d = *(const uint2*)(hb + row * F + m16 * 4);
            *(uint2*)(Hout + (size_t)(row0 + row) * F + m16 * 4) = d;
        }
        v8s a2[2];
#pragma unroll
        for (int kc = 0; kc < 2; ++kc)
            a2[kc] = *(const v8s*)(hb + m16 * F + kc * 32 + quad * 8);
#pragma unroll
        for (int nt = 0; nt < 4; ++nt) {
            v4f acc;
#pragma unroll
            for (int reg = 0; reg < 4; ++reg)
                acc[reg] = Yf[(size_t)(row0 + quad * 4 + reg) * F + nt * 16 + m16];
            acc = __builtin_amdgcn_mfma_f32_16x16x32_bf16(a2[0], bfj_[nt][0], acc, 0, 0, 0);
            acc = __builtin_amdgcn_mfma_f32_16x16x32_bf16(a2[1], bfj_[nt][1], acc, 0, 0, 0);
            float ss1 = 0.f, ss2 = 0.f;
#pragma unroll
            for (int reg = 0; reg < 4; ++reg) {
                float yv = acc[reg];
                Yf[(size_t)(row0 + quad * 4 + reg) * F + nt * 16 + m16] = yv;
                ss1 += yv;
                ss2 += yv * yv;
            }
            s1v[nt] = ss1;
            s2v[nt] = ss2;
        }
    }
    if (doHead) {
        if (t < F) { cred1[t] = 0.f; cred2[t] = 0.f; }
        __syncthreads();
        if (row0 < N) {
#pragma unroll
            for (int nt = 0; nt < 4; ++nt) {
                atomicAdd(&cred1[nt * 16 + m16], s1v[nt]);
                atomicAdd(&cred2[nt * 16 + m16], s2v[nt]);
            }
        }
        __syncthreads();
        if (t < F) {
            atomicAdd(&stats5[t], cred1[t]);
            atomicAdd(&stats5[F + t], cred2[t]);
        }
    }
}

// ---- MFMA head: BN(Yf)+ReLU -> @mlpW2+b2 -> pooled add into out[graph] --
__global__ __launch_bounds__(TPB, 4)
void k_final(const float* __restrict__ Yf, const float* __restrict__ stats,
             const float* __restrict__ g, const float* __restrict__ bt,
             const float* __restrict__ W2, const float* __restrict__ b2,
             const int* __restrict__ batch, float* __restrict__ out, int N) {
    __shared__ u16 W2l[F * F];
    __shared__ float scs[F], shs[F];
    int t = threadIdx.x;
    int lane = t & 63, w = t >> 6;
    int m16 = lane & 15, quad = lane >> 4;
    for (int i = t; i < F * F; i += TPB) W2l[i] = f2bf(W2[i]);
    if (t < F) {
        float mu = stats[t] / (float)N;
        float var = stats[F + t] / (float)N - mu * mu;
        float rs = rsqrtf(var + BN_EPS);
        float sc = rs * g[t];
        scs[t] = sc;
        shs[t] = bt[t] - mu * sc;
    }
    __syncthreads();
    int row0 = (blockIdx.x * 4 + w) * 16;
    if (row0 >= N) return;
    v8s bw[4][2];
#pragma unroll
    for (int nt = 0; nt < 4; ++nt)
#pragma unroll
        for (int kc = 0; kc < 2; ++kc)
#pragma unroll
            for (int j = 0; j < 8; ++j)
                bw[nt][kc][j] = (short)W2l[(kc * 32 + quad * 8 + j) * F + nt * 16 + m16];
    v8s a[2];
#pragma unroll
    for (int kc = 0; kc < 2; ++kc) {
        const float* yp = Yf + (size_t)(row0 + m16) * F + kc * 32 + quad * 8;
        float4 r0 = *(const float4*)yp;
        float4 r1 = *(const float4*)(yp + 4);
        float vals[8] = {r0.x, r0.y, r0.z, r0.w, r1.x, r1.y, r1.z, r1.w};
#pragma unroll
        for (int j = 0; j < 8; ++j) {
            int k = kc * 32 + quad * 8 + j;
            a[kc][j] = (short)f2bf(fmaxf(vals[j] * scs[k] + shs[k], 0.f));
        }
    }
    v4f accv[4];
#pragma unroll
    for (int nt = 0; nt < 4; ++nt) {
        float bb = b2[nt * 16 + m16];
        v4f acc = {bb, bb, bb, bb};
        acc = __builtin_amdgcn_mfma_f32_16x16x32_bf16(a[0], bw[nt][0], acc, 0, 0, 0);
        acc = __builtin_amdgcn_mfma_f32_16x16x32_bf16(a[1], bw[nt][1], acc, 0, 0, 0);
        accv[nt] = acc;
    }
    int gid_prev = -1;
    float psum[4] = {0.f, 0.f, 0.f, 0.f};
#pragma unroll
    for (int reg = 0; reg < 4; ++reg) {
        int gid = batch[row0 + quad * 4 + reg];
        if (gid != gid_prev) {
            if (gid_prev >= 0)
#pragma unroll
                for (int nt = 0; nt < 4; ++nt)
                    atomicAdd(&out[(size_t)gid_prev * F + nt * 16 + m16], psum[nt]);
            gid_prev = gid;
            psum[0] = psum[1] = psum[2] = psum[3] = 0.f;
        }
#pragma unroll
        for (int nt = 0; nt < 4; ++nt) psum[nt] += accv[nt][reg];
    }
    if (gid_prev >= 0)
#pragma unroll
        for (int nt = 0; nt < 4; ++nt)
            atomicAdd(&out[(size_t)gid_prev * F + nt * 16 + m16], psum[nt]);
}

// ---- launcher -----------------------------------------------------------

extern "C" void kernel_launch(void* const* d_in, const int* in_sizes, int n_in,
                              void* d_out, int out_size, void* d_ws, size_t ws_size,
                              hipStream_t stream) {
    const float* x      = (const float*)d_in[0];
    const int*   ei     = (const int*)d_in[1];
    const int*   batch  = (const int*)d_in[2];
    const float* convW1 = (const float*)d_in[3];
    const float* convb1 = (const float*)d_in[4];
    const float* convg  = (const float*)d_in[5];
    const float* convbt = (const float*)d_in[6];
    const float* convW2 = (const float*)d_in[7];
    const float* convb2 = (const float*)d_in[8];
    const float* mlpW1  = (const float*)d_in[9];
    const float* mlpb1  = (const float*)d_in[10];
    const float* mlpg   = (const float*)d_in[11];
    const float* mlpbt  = (const float*)d_in[12];
    const float* mlpW2  = (const float*)d_in[13];
    const float* mlpb2  = (const float*)d_in[14];

    const int N = in_sizes[0] / F;             // 50000
    const int E = in_sizes[1] / 2;             // 800000
    const int L = in_sizes[3] / (F * F);       // 5

    const int* src = ei;
    const int* dst = ei + E;

    char* w = (char*)d_ws;
    size_t off = 0;
    auto alloc = [&](size_t bytes) {
        void* p = w + off;
        off = (off + bytes + 255) & ~(size_t)255;
        return p;
    };
    u16*   x16     = (u16*)alloc((size_t)N * F * 2);
    u16*   hA16    = (u16*)alloc((size_t)N * F * 2);
    u16*   hB16    = (u16*)alloc((size_t)N * F * 2);
    u16*   Ytmp16  = (u16*)alloc((size_t)N * F * 2);
    float* Yf      = (float*)alloc((size_t)N * F * 4);
    int*   deg     = (int*)alloc((size_t)N * 4);
    int*   offs    = (int*)alloc((size_t)(N + 1) * 4);
    int*   cursor  = (int*)alloc((size_t)N * 4);
    int*   csr_src = (int*)alloc((size_t)E * 4);
    int*   part    = (int*)alloc((size_t)SCAN_B * 4);
    float* stats   = (float*)alloc((size_t)(L + 1) * 128 * 4);

    hipMemsetAsync(deg, 0, (size_t)N * 4, stream);
    hipMemsetAsync(stats, 0, (size_t)(L + 1) * 128 * 4, stream);
    hipMemsetAsync(d_out, 0, (size_t)out_size * 4, stream);

    const int edgeBlocks = (E + TPB - 1) / TPB;

    k_hist<<<edgeBlocks, TPB, 0, stream>>>(dst, deg, E);
    k_scan_part<<<SCAN_B, TPB, 0, stream>>>(deg, part, N);
    k_scan_apply<<<SCAN_B, TPB, 0, stream>>>(deg, part, offs, cursor, N);
    k_fill<<<edgeBlocks, TPB, 0, stream>>>(src, dst, cursor, csr_src, E);

    const int blocksA = (N + 4 * NPW - 1) / (4 * NPW);   // 1563
    const int blocksB = (N + 63) / 64;                   // MFMA tiles

    k_prep<<<blocksB, TPB, 0, stream>>>(x, x16, mlpW1, mlpb1, Yf, N);

    const u16* h_cur = x16;
    for (int l = 0; l < L; ++l) {
        u16* h_next = (l & 1) ? hB16 : hA16;
        k_gather_gemm<<<blocksA, TPB, 0, stream>>>(h_cur, offs, csr_src,
                                                   convW1 + l * F * F, convb1 + l * F,
                                                   Ytmp16, stats + l * 128, N);
        k_layerB<<<blocksB, TPB, 0, stream>>>(Ytmp16, stats + l * 128,
                                              convg + l * F, convbt + l * F,
                                              convW2 + l * F * F, convb2 + l * F,
                                              mlpW1 + (l + 1) * F * F,
                                              h_next, Yf, stats + L * 128,
                                              N, l == L - 1);
        h_cur = h_next;
    }

    k_final<<<blocksB, TPB, 0, stream>>>(Yf, stats + L * 128, mlpg, mlpbt,
                                         mlpW2, mlpb2, batch, (float*)d_out, N);
}